// Round 29
// baseline (428.933 us; speedup 1.0000x reference)
//
#include <hip/hip_runtime.h>

#define NUM_USER   50000
#define NUM_ITEM   50000
#define NUM_NODES  100000
#define DIM_LATENT 256
#define DIM_ID     64
#define NUM_EDGES  2000000
#define NBUCKET    391        // ceil(100000/256) buckets of 256 nodes
#define BPB        4096       // edges per chunk for counting sort
#define NCHUNK     489        // ceil(NUM_EDGES/BPB)
#define HSTRIDE    392
#define MAXBKT     8192       // max edges per bucket staged in LDS (avg 5115, ~37 sigma margin)
#define ZROW       NUM_NODES  // sentinel zero row in fp8 table

typedef __attribute__((ext_vector_type(8))) short bf8_t;
typedef __attribute__((ext_vector_type(4))) float f4_t;
typedef __attribute__((ext_vector_type(2))) float f2_t;

static __device__ __forceinline__ float lrelu(float x) {
    return x > 0.0f ? x : 0.01f * x;
}
static __device__ __forceinline__ unsigned short f2bf(float f) {
    unsigned u = __float_as_uint(f);
    u += 0x7fff + ((u >> 16) & 1);
    return (unsigned short)(u >> 16);
}
static __device__ __forceinline__ unsigned cvtpk_bf16(float lo, float hi) {
    unsigned r;
    asm("v_cvt_pk_bf16_f32 %0, %1, %2" : "=v"(r) : "v"(lo), "v"(hi));
    return r;
}
static __device__ __forceinline__ float bf2f(unsigned short u) {
    return __uint_as_float(((unsigned)u) << 16);
}
static __device__ __forceinline__ float bflo(unsigned u) {
    return __uint_as_float(u << 16);
}
static __device__ __forceinline__ float bfhi(unsigned u) {
    return __uint_as_float(u & 0xffff0000u);
}
static __device__ __forceinline__ f2_t shfl2(f2_t v, int off) {
    long long l = __shfl_xor(__builtin_bit_cast(long long, v), off);
    return __builtin_bit_cast(f2_t, l);
}

// ---------------- pass 1: per-chunk bucket histogram (LDS atomics only) ----------------
__global__ void __launch_bounds__(256) k_hist(const int* __restrict__ row,
                                              int* __restrict__ hist) {
    __shared__ int lh[NBUCKET];
    const int g = blockIdx.x, t = threadIdx.x;
    for (int i = t; i < NBUCKET; i += 256) lh[i] = 0;
    __syncthreads();
    const int base = g * BPB;
    for (int i = 0; i < BPB; i += 256) {
        int e = base + i + t;
        if (e < NUM_EDGES) atomicAdd(&lh[row[e] >> 8], 1);
    }
    __syncthreads();
    for (int i = t; i < NBUCKET; i += 256) hist[g * HSTRIDE + i] = lh[i];
}

// ---------------- pass 2a: per-bucket scan over 489 chunks (512 threads) ----------------
__global__ void __launch_bounds__(512) k_off1(int* __restrict__ hist,
                                              int* __restrict__ bcnt) {
    __shared__ int wsum[8];
    const int b = blockIdx.x, t = threadIdx.x;
    const int lane = t & 63, w = t >> 6;
    int c = (t < NCHUNK) ? hist[t * HSTRIDE + b] : 0;
    int v = c;
    #pragma unroll
    for (int off = 1; off < 64; off <<= 1) {
        int u = __shfl_up(v, off);
        if (lane >= off) v += u;
    }
    if (lane == 63) wsum[w] = v;
    __syncthreads();
    int add = 0;
    #pragma unroll
    for (int i = 0; i < 8; ++i) if (i < w) add += wsum[i];
    int incl = v + add;
    if (t < NCHUNK) hist[t * HSTRIDE + b] = incl - c;
    if (t == 511) bcnt[b] = incl;
}

// ---------------- pass 2b: exclusive scan over 391 bucket counts -> boff ----------------
__global__ void __launch_bounds__(512) k_bscan(const int* __restrict__ bcnt,
                                               int* __restrict__ boff) {
    __shared__ int wsum[8];
    const int t = threadIdx.x;
    const int lane = t & 63, w = t >> 6;
    int c = (t < NBUCKET) ? bcnt[t] : 0;
    int v = c;
    #pragma unroll
    for (int off = 1; off < 64; off <<= 1) {
        int u = __shfl_up(v, off);
        if (lane >= off) v += u;
    }
    if (lane == 63) wsum[w] = v;
    __syncthreads();
    int add = 0;
    #pragma unroll
    for (int i = 0; i < 8; ++i) if (i < w) add += wsum[i];
    int ex = v + add - c;
    if (t < NBUCKET) boff[t] = ex;
    if (t == NBUCKET - 1) boff[NBUCKET] = ex + c;   // == NUM_EDGES
}

// ---------------- pass 3: scatter packed edges to bucket-contiguous epk ----------------
// pack: (local_node << 24) | col   (col < 2^17)
__global__ void __launch_bounds__(256) k_bin2(const int* __restrict__ row,
                                              const int* __restrict__ col,
                                              const int* __restrict__ hist,
                                              const int* __restrict__ boff,
                                              unsigned* __restrict__ epk) {
    __shared__ int curs[NBUCKET];
    const int g = blockIdx.x, t = threadIdx.x;
    for (int i = t; i < NBUCKET; i += 256) curs[i] = boff[i] + hist[g * HSTRIDE + i];
    __syncthreads();
    const int base = g * BPB;
    for (int i = 0; i < BPB; i += 256) {
        int e = base + i + t;
        if (e < NUM_EDGES) {
            int r = row[e];
            int pos = atomicAdd(&curs[r >> 8], 1);
            epk[pos] = ((unsigned)(r & 255) << 24) | (unsigned)col[e];
        }
    }
}

// ---------------- pass 4: IN-PLACE bucket-local exact CSR via LDS staging ----------------
__global__ void __launch_bounds__(512) k_csr(unsigned* __restrict__ epk,
                                             const int* __restrict__ boff,
                                             int* __restrict__ offs,
                                             int* __restrict__ cnt,
                                             float* __restrict__ dis) {
    __shared__ unsigned stage[MAXBKT];   // 32 KB
    __shared__ int lcnt[256];
    __shared__ int lofs[256];
    __shared__ int wsum[4];
    const int b = blockIdx.x, t = threadIdx.x;
    const int start = boff[b];
    int m = boff[b + 1] - start;
    if (m > MAXBKT) m = MAXBKT;          // statistically unreachable guard

    if (t < 256) lcnt[t] = 0;
    for (int e = t; e < m; e += 512) stage[e] = epk[start + e];
    __syncthreads();
    for (int e = t; e < m; e += 512) atomicAdd(&lcnt[stage[e] >> 24], 1);
    __syncthreads();

    const int lane = t & 63, w = t >> 6;
    int c = (t < 256) ? lcnt[t] : 0;
    int v = c;
    #pragma unroll
    for (int off = 1; off < 64; off <<= 1) {
        int u = __shfl_up(v, off);
        if (lane >= off) v += u;
    }
    if (t < 256 && lane == 63) wsum[w] = v;
    __syncthreads();
    if (t < 256) {
        int add = 0;
        #pragma unroll
        for (int i = 0; i < 4; ++i) if (i < w) add += wsum[i];
        int ex = v + add - c;
        lofs[t] = start + ex;
        int n = (b << 8) + t;
        if (n < NUM_NODES) {
            offs[n] = start + ex;
            cnt[n]  = c;
            dis[n]  = rsqrtf((float)max(c, 1));
        }
    }
    __syncthreads();
    for (int e = t; e < m; e += 512) {
        unsigned p = stage[e];
        int pos = atomicAdd(&lofs[p >> 24], 1);
        epk[pos] = p & 0x00ffffffu;      // becomes ecol
    }
}

// ---------------- weight prep: Wg0,lw0 -> bf16 fragment table; block 0 zeroes sentinel ----------------
__global__ void __launch_bounds__(256) k_wprep(const float* __restrict__ Wg,
                                               const float* __restrict__ Wl,
                                               unsigned short* __restrict__ wfrag,
                                               unsigned* __restrict__ hbf8z) {
    if (blockIdx.x == 0 && threadIdx.x < 16)
        hbf8z[(size_t)ZROW * 16 + threadIdx.x] = 0u;   // 64B zero row
    int g = blockIdx.x * 256 + threadIdx.x;     // 4096 total
    if (g >= 4096) return;
    int ks = g >> 9;
    int t  = (g >> 6) & 7;
    int l  = g & 63;
    const float* W = (t < 4) ? Wg : Wl;
    int colg = (t & 3) * 16 + (l & 15);
    int kb = ks * 32 + (l >> 4) * 8;
    unsigned short o[8];
    #pragma unroll
    for (int e = 0; e < 8; ++e) o[e] = f2bf(W[(size_t)(kb + e) * DIM_ID + colg]);
    unsigned short* dst = wfrag + (size_t)g * 8;
    #pragma unroll
    for (int e = 0; e < 8; ++e) dst[e] = o[e];
}

// ---------------- weight prep: 4x 64x64 weights -> bf16 fragment tables ----------------
__global__ void __launch_bounds__(256) k_wprep64(const float* __restrict__ W0,
                                                 const float* __restrict__ W1,
                                                 const float* __restrict__ W2,
                                                 const float* __restrict__ W3,
                                                 unsigned short* __restrict__ frag) {
    int g = blockIdx.x * 256 + threadIdx.x;     // 2048 total
    if (g >= 2048) return;
    int m = g >> 9;
    int r = g & 511;
    int ks = r >> 8;
    int t  = (r >> 6) & 3;
    int l  = r & 63;
    const float* W = (m == 0) ? W0 : (m == 1) ? W1 : (m == 2) ? W2 : W3;
    int colg = t * 16 + (l & 15);
    int kb = ks * 32 + (l >> 4) * 8;
    unsigned short o[8];
    #pragma unroll
    for (int e = 0; e < 8; ++e) o[e] = f2bf(W[(size_t)(kb + e) * DIM_ID + colg]);
    unsigned short* dst = frag + (size_t)g * 8;
    #pragma unroll
    for (int e = 0; e < 8; ++e) dst[e] = o[e];
}

// ---------------- layer 1 (MFMA): K-SPLIT across 4 waves, LDS f32 ATOMIC reduction ----------------
// Block = 16 rows, 4 waves; wave w covers K in [64w, 64w+64) -> 4 float4 loads/wave.
// Partials merge via native ds_add_f32 into ONE shared accw[32][64] (8 KB) instead of
// 4 private copies (32 KB) -> total LDS ~12.8 KB -> 8 blocks/CU (wave-capped, 2x r28).
// Same f32 arithmetic; only the summation order varies (rounding-level difference).
__global__ void __launch_bounds__(256, 8) k_l1(
    const float* __restrict__ pref, const float* __restrict__ feat,
    const unsigned short* __restrict__ wfrag,
    const float* __restrict__ lb,   const float* __restrict__ idemb,
    const float* __restrict__ dis,
    unsigned char* __restrict__ hbf8, unsigned short* __restrict__ xhat)
{
    __shared__ float accw[32][64];           // 8 KB summed C tile [t*4+reg][lane]
    __shared__ float ssb[4][16];             // per-wave row sq-sums
    __shared__ unsigned short stA[16][68];   // staged h (bf16, pre-fp8)
    __shared__ unsigned short stB[16][68];   // staged xhat (bf16, pre-idemb)
    const int t256 = threadIdx.x;
    const int lane = t256 & 63;
    const int w = t256 >> 6;                 // K-quarter 0..3
    const int ql = lane & 15, q = lane >> 4;
    const int rowBase = blockIdx.x * 16;
    const int rown = rowBase + ql;
    const float* src = (rown < NUM_USER) ? (pref + (size_t)rown * DIM_LATENT)
                                         : (feat + (size_t)(rown - NUM_USER) * DIM_LATENT);
    const int ks0 = 2 * w;

    // 4 loads per wave (compiler keeps these in flight)
    float4 v0 = *reinterpret_cast<const float4*>(src + ks0 * 32 + q * 8);
    float4 v1 = *reinterpret_cast<const float4*>(src + ks0 * 32 + q * 8 + 4);
    float4 v2 = *reinterpret_cast<const float4*>(src + (ks0 + 1) * 32 + q * 8);
    float4 v3 = *reinterpret_cast<const float4*>(src + (ks0 + 1) * 32 + q * 8 + 4);

    // zero the shared accumulator (independent of loads -> overlaps their latency)
    #pragma unroll
    for (int i = 0; i < 8; ++i)
        reinterpret_cast<float*>(accw)[i * 256 + t256] = 0.0f;

    // partial squared-sum of row ql over this wave's K-range
    float ss = v0.x*v0.x + v0.y*v0.y + v0.z*v0.z + v0.w*v0.w
             + v1.x*v1.x + v1.y*v1.y + v1.z*v1.z + v1.w*v1.w
             + v2.x*v2.x + v2.y*v2.y + v2.z*v2.z + v2.w*v2.w
             + v3.x*v3.x + v3.y*v3.y + v3.z*v3.z + v3.w*v3.w;
    ss += __shfl_xor(ss, 16);
    ss += __shfl_xor(ss, 32);
    if (lane < 16) ssb[w][lane] = ss;

    // raw bf16 fragments for the 2 K-steps
    uint4 au0, au1;
    au0.x = cvtpk_bf16(v0.x, v0.y); au0.y = cvtpk_bf16(v0.z, v0.w);
    au0.z = cvtpk_bf16(v1.x, v1.y); au0.w = cvtpk_bf16(v1.z, v1.w);
    au1.x = cvtpk_bf16(v2.x, v2.y); au1.y = cvtpk_bf16(v2.z, v2.w);
    au1.z = cvtpk_bf16(v3.x, v3.y); au1.w = cvtpk_bf16(v3.z, v3.w);
    bf8_t a0 = __builtin_bit_cast(bf8_t, au0);
    bf8_t a1 = __builtin_bit_cast(bf8_t, au1);

    f4_t acc[8];
    #pragma unroll
    for (int t = 0; t < 8; ++t) acc[t] = (f4_t){0.f, 0.f, 0.f, 0.f};

    const bf8_t* wf = reinterpret_cast<const bf8_t*>(wfrag);
    #pragma unroll
    for (int t = 0; t < 8; ++t)
        acc[t] = __builtin_amdgcn_mfma_f32_16x16x32_bf16(a0, wf[(ks0 * 8 + t) * 64 + lane], acc[t], 0, 0, 0);
    #pragma unroll
    for (int t = 0; t < 8; ++t)
        acc[t] = __builtin_amdgcn_mfma_f32_16x16x32_bf16(a1, wf[((ks0 + 1) * 8 + t) * 64 + lane], acc[t], 0, 0, 0);

    __syncthreads();   // zeros (and ssb) visible block-wide before atomic merge

    // merge partials: native ds_add_f32; each address hit by exactly 4 threads (1/wave)
    #pragma unroll
    for (int t = 0; t < 8; ++t)
        #pragma unroll
        for (int reg = 0; reg < 4; ++reg)
            atomicAdd(&accw[t * 4 + reg][lane], acc[t][reg]);
    __syncthreads();

    // rn per C-layout row q*4+reg (sum ss over 4 waves)
    float rnl[4];
    #pragma unroll
    for (int reg = 0; reg < 4; ++reg) {
        int r = q * 4 + reg;
        float s = (ssb[0][r] + ssb[1][r]) + (ssb[2][r] + ssb[3][r]);
        rnl[reg] = 1.0f / fmaxf(sqrtf(s), 1e-12f);
    }

    // finalize this wave's two tiles t = 2w, 2w+1 (accw already holds the full sum)
    #pragma unroll
    for (int j = 0; j < 2; ++j) {
        int t = ks0 + j;
        float av[4];
        #pragma unroll
        for (int reg = 0; reg < 4; ++reg)
            av[reg] = accw[t * 4 + reg][lane];
        if (t < 4) {
            int colg = t * 16 + ql;
            #pragma unroll
            for (int reg = 0; reg < 4; ++reg) {
                float dn = dis[rowBase + q * 4 + reg] * rnl[reg];
                stA[q * 4 + reg][colg] = f2bf(av[reg] * dn);
            }
        } else {
            int colg = (t - 4) * 16 + ql;
            float lbl = lb[colg];
            #pragma unroll
            for (int reg = 0; reg < 4; ++reg)
                stB[q * 4 + reg][colg] = f2bf(lrelu(av[reg] * rnl[reg] + lbl));
        }
    }
    __syncthreads();

    // writeout hbf8: 16 rows x 16 uints; one per thread
    {
        int r = t256 >> 4, c8 = t256 & 15;
        int n = rowBase + r;
        uint2 s = *reinterpret_cast<const uint2*>(&stA[r][c8 * 4]);
        int p = __builtin_amdgcn_cvt_pk_fp8_f32(bflo(s.x), bfhi(s.x), 0, false);
        p = __builtin_amdgcn_cvt_pk_fp8_f32(bflo(s.y), bfhi(s.y), p, true);
        *reinterpret_cast<unsigned*>(hbf8 + (size_t)n * DIM_ID + c8 * 4) = (unsigned)p;
    }
    // writeout xhat: 16 rows x 16 uint2 (+idemb); one per thread
    {
        int r = t256 >> 4, c8 = t256 & 15;
        int n = rowBase + r;
        uint2 s = *reinterpret_cast<const uint2*>(&stB[r][c8 * 4]);
        float4 idv = *reinterpret_cast<const float4*>(&idemb[(size_t)n * DIM_ID + c8 * 4]);
        uint2 o;
        o.x = cvtpk_bf16(bflo(s.x) + idv.x, bfhi(s.x) + idv.y);
        o.y = cvtpk_bf16(bflo(s.y) + idv.z, bfhi(s.y) + idv.w);
        *reinterpret_cast<uint2*>(&xhat[(size_t)n * DIM_ID + c8 * 4]) = o;
    }
}

// ---------------- gather: Hb[n] = bf16(dis[n] * sum_e hbf8[ecol[e]]) ----------------
// eighth-wave per edge; OOB slots read sentinel zero-row -> unpredicated inner loop
__global__ void __launch_bounds__(256, 8) k_gather(
    const unsigned char* __restrict__ hbf8, const float* __restrict__ dis,
    const int* __restrict__ offs, const int* __restrict__ cnt,
    const int* __restrict__ ecol, unsigned short* __restrict__ Hb)
{
    const int w = threadIdx.x >> 6;
    const int lane = threadIdx.x & 63;
    const int g = lane >> 3;      // edge slot 0..7
    const int k = lane & 7;       // dim octet 0..7
    const int n = blockIdx.x * 4 + w;

    const float dn = dis[n];
    const int start = offs[n];
    const int m = cnt[n];

    f2_t s01 = {0.f, 0.f}, s23 = {0.f, 0.f}, s45 = {0.f, 0.f}, s67 = {0.f, 0.f};

    for (int base = 0; base < m; base += 64) {
        int e = base + lane;
        int ec = (e < m) ? ecol[start + e] : ZROW;
        int lim = m - base; if (lim > 64) lim = 64;
        int ns = (lim + 31) >> 5;
        for (int s = 0; s < ns; ++s) {
            int i0 = s * 32 + g;
            int c0 = __shfl(ec, i0);
            int c1 = __shfl(ec, i0 + 8);
            int c2 = __shfl(ec, i0 + 16);
            int c3 = __shfl(ec, i0 + 24);
            uint2 u0 = *reinterpret_cast<const uint2*>(hbf8 + (size_t)(c0 << 6) + (k << 3));
            uint2 u1 = *reinterpret_cast<const uint2*>(hbf8 + (size_t)(c1 << 6) + (k << 3));
            uint2 u2 = *reinterpret_cast<const uint2*>(hbf8 + (size_t)(c2 << 6) + (k << 3));
            uint2 u3 = *reinterpret_cast<const uint2*>(hbf8 + (size_t)(c3 << 6) + (k << 3));
            s01 += __builtin_amdgcn_cvt_pk_f32_fp8(u0.x, false);
            s23 += __builtin_amdgcn_cvt_pk_f32_fp8(u0.x, true);
            s45 += __builtin_amdgcn_cvt_pk_f32_fp8(u0.y, false);
            s67 += __builtin_amdgcn_cvt_pk_f32_fp8(u0.y, true);
            s01 += __builtin_amdgcn_cvt_pk_f32_fp8(u1.x, false);
            s23 += __builtin_amdgcn_cvt_pk_f32_fp8(u1.x, true);
            s45 += __builtin_amdgcn_cvt_pk_f32_fp8(u1.y, false);
            s67 += __builtin_amdgcn_cvt_pk_f32_fp8(u1.y, true);
            s01 += __builtin_amdgcn_cvt_pk_f32_fp8(u2.x, false);
            s23 += __builtin_amdgcn_cvt_pk_f32_fp8(u2.x, true);
            s45 += __builtin_amdgcn_cvt_pk_f32_fp8(u2.y, false);
            s67 += __builtin_amdgcn_cvt_pk_f32_fp8(u2.y, true);
            s01 += __builtin_amdgcn_cvt_pk_f32_fp8(u3.x, false);
            s23 += __builtin_amdgcn_cvt_pk_f32_fp8(u3.x, true);
            s45 += __builtin_amdgcn_cvt_pk_f32_fp8(u3.y, false);
            s67 += __builtin_amdgcn_cvt_pk_f32_fp8(u3.y, true);
        }
    }
    #pragma unroll
    for (int off = 8; off <= 32; off <<= 1) {
        s01 += shfl2(s01, off);
        s23 += shfl2(s23, off);
        s45 += shfl2(s45, off);
        s67 += shfl2(s67, off);
    }
    if (lane < 8) {
        uint4 o;
        o.x = cvtpk_bf16(s01.x * dn, s01.y * dn);
        o.y = cvtpk_bf16(s23.x * dn, s23.y * dn);
        o.z = cvtpk_bf16(s45.x * dn, s45.y * dn);
        o.w = cvtpk_bf16(s67.x * dn, s67.y * dn);
        *reinterpret_cast<uint4*>(&Hb[(size_t)n * DIM_ID + lane * 8]) = o;
    }
}

// ---------------- mid (MFMA): x1 = lrelu(lrelu(H)@gw0+gb0+xhat1);
//                  hbf8 = fp8(dis*(x1@Wg1)); xhat2 = bf16(lrelu(x1@lw1+b1)+id) ----------------
__global__ void __launch_bounds__(256, 3) k_mid(
    const unsigned short* __restrict__ Hb, const unsigned short* __restrict__ xhat1,
    const unsigned short* __restrict__ wf64,
    const float* __restrict__ gb,  const float* __restrict__ lb1,
    const float* __restrict__ idemb, const float* __restrict__ dis,
    unsigned char* __restrict__ hbf8, unsigned short* __restrict__ xhat2)
{
    __shared__ unsigned short x1s[4][16][DIM_ID];
    __shared__ unsigned short st[4][16][68];
    const int lane = threadIdx.x & 63;
    const int w = threadIdx.x >> 6;
    const int ql = lane & 15, q = lane >> 4;
    const int rowBase = (blockIdx.x * 4 + w) * 16;
    const int rowc = min(rowBase + ql, NUM_NODES - 1);

    bf8_t ha[2];
    #pragma unroll
    for (int ks = 0; ks < 2; ++ks) {
        uint4 u = *reinterpret_cast<const uint4*>(&Hb[(size_t)rowc * DIM_ID + ks * 32 + q * 8]);
        bf8_t a;
        a[0] = (short)f2bf(lrelu(bflo(u.x))); a[1] = (short)f2bf(lrelu(bfhi(u.x)));
        a[2] = (short)f2bf(lrelu(bflo(u.y))); a[3] = (short)f2bf(lrelu(bfhi(u.y)));
        a[4] = (short)f2bf(lrelu(bflo(u.z))); a[5] = (short)f2bf(lrelu(bfhi(u.z)));
        a[6] = (short)f2bf(lrelu(bflo(u.w))); a[7] = (short)f2bf(lrelu(bfhi(u.w)));
        ha[ks] = a;
    }

    const bf8_t* gw0f = reinterpret_cast<const bf8_t*>(wf64);
    f4_t acc1[4];
    #pragma unroll
    for (int t = 0; t < 4; ++t) acc1[t] = (f4_t){0.f, 0.f, 0.f, 0.f};
    #pragma unroll
    for (int ks = 0; ks < 2; ++ks)
        #pragma unroll
        for (int t = 0; t < 4; ++t)
            acc1[t] = __builtin_amdgcn_mfma_f32_16x16x32_bf16(ha[ks], gw0f[(ks * 4 + t) * 64 + lane], acc1[t], 0, 0, 0);

    int nn[4];
    #pragma unroll
    for (int reg = 0; reg < 4; ++reg) nn[reg] = rowBase + q * 4 + reg;

    #pragma unroll
    for (int t = 0; t < 4; ++t) {
        int colg = t * 16 + ql;
        float gbl = gb[colg];
        #pragma unroll
        for (int reg = 0; reg < 4; ++reg) {
            float xh = bf2f(xhat1[(size_t)min(nn[reg], NUM_NODES - 1) * DIM_ID + colg]);
            x1s[w][q * 4 + reg][colg] = f2bf(lrelu(acc1[t][reg] + gbl + xh));
        }
    }
    __syncthreads();

    bf8_t xa[2];
    #pragma unroll
    for (int ks = 0; ks < 2; ++ks)
        xa[ks] = *reinterpret_cast<const bf8_t*>(&x1s[w][ql][ks * 32 + q * 8]);

    const bf8_t* wg1f = reinterpret_cast<const bf8_t*>(wf64 + 512 * 8);
    const bf8_t* lw1f = reinterpret_cast<const bf8_t*>(wf64 + 1024 * 8);
    f4_t acc2[8];
    #pragma unroll
    for (int t = 0; t < 8; ++t) acc2[t] = (f4_t){0.f, 0.f, 0.f, 0.f};
    #pragma unroll
    for (int ks = 0; ks < 2; ++ks) {
        #pragma unroll
        for (int t = 0; t < 4; ++t)
            acc2[t] = __builtin_amdgcn_mfma_f32_16x16x32_bf16(xa[ks], wg1f[(ks * 4 + t) * 64 + lane], acc2[t], 0, 0, 0);
        #pragma unroll
        for (int t = 0; t < 4; ++t)
            acc2[4 + t] = __builtin_amdgcn_mfma_f32_16x16x32_bf16(xa[ks], lw1f[(ks * 4 + t) * 64 + lane], acc2[4 + t], 0, 0, 0);
    }

    float dn[4];
    #pragma unroll
    for (int reg = 0; reg < 4; ++reg)
        dn[reg] = (nn[reg] < NUM_NODES) ? dis[nn[reg]] : 0.0f;

    // ---- phase A: hbf8 = fp8(acc2[0..3]*dn) via LDS -> coalesced uint ----
    #pragma unroll
    for (int t = 0; t < 4; ++t)
        #pragma unroll
        for (int reg = 0; reg < 4; ++reg)
            st[w][q * 4 + reg][t * 16 + ql] = f2bf(acc2[t][reg] * dn[reg]);
    #pragma unroll
    for (int it = 0; it < 4; ++it) {
        int i = it * 64 + lane;
        int r = i >> 4, c8 = i & 15;
        int n = rowBase + r;
        uint2 s = *reinterpret_cast<const uint2*>(&st[w][r][c8 * 4]);
        if (n < NUM_NODES) {
            int p = __builtin_amdgcn_cvt_pk_fp8_f32(bflo(s.x), bfhi(s.x), 0, false);
            p = __builtin_amdgcn_cvt_pk_fp8_f32(bflo(s.y), bfhi(s.y), p, true);
            *reinterpret_cast<unsigned*>(hbf8 + (size_t)n * DIM_ID + c8 * 4) = (unsigned)p;
        }
    }

    // ---- phase B: xhat2 = lrelu(acc2[4..7]+lb1) (+idemb coalesced) ----
    #pragma unroll
    for (int t = 0; t < 4; ++t) {
        int colg = t * 16 + ql;
        float lbl = lb1[colg];
        #pragma unroll
        for (int reg = 0; reg < 4; ++reg)
            st[w][q * 4 + reg][colg] = f2bf(lrelu(acc2[4 + t][reg] + lbl));
    }
    #pragma unroll
    for (int it = 0; it < 4; ++it) {
        int i = it * 64 + lane;
        int r = i >> 4, c8 = i & 15;
        int n = rowBase + r;
        if (n < NUM_NODES) {
            uint2 s = *reinterpret_cast<const uint2*>(&st[w][r][c8 * 4]);
            float4 idv = *reinterpret_cast<const float4*>(&idemb[(size_t)n * DIM_ID + c8 * 4]);
            uint2 o;
            o.x = cvtpk_bf16(bflo(s.x) + idv.x, bfhi(s.x) + idv.y);
            o.y = cvtpk_bf16(bflo(s.y) + idv.z, bfhi(s.y) + idv.w);
            *reinterpret_cast<uint2*>(&xhat2[(size_t)n * DIM_ID + c8 * 4]) = o;
        }
    }
}

// ---------------- final (MFMA): out = lrelu(lrelu(H2)@gw1 + gb1 + xhat2) ----------------
__global__ void __launch_bounds__(256, 3) k_final(
    const unsigned short* __restrict__ Hb, const unsigned short* __restrict__ xhat,
    const unsigned short* __restrict__ wf64,
    const float* __restrict__ gb, float* __restrict__ out)
{
    const int lane = threadIdx.x & 63;
    const int w = threadIdx.x >> 6;
    const int ql = lane & 15, q = lane >> 4;
    const int rowBase = (blockIdx.x * 4 + w) * 16;
    const int rowc = min(rowBase + ql, NUM_NODES - 1);

    bf8_t ha[2];
    #pragma unroll
    for (int ks = 0; ks < 2; ++ks) {
        uint4 u = *reinterpret_cast<const uint4*>(&Hb[(size_t)rowc * DIM_ID + ks * 32 + q * 8]);
        bf8_t a;
        a[0] = (short)f2bf(lrelu(bflo(u.x))); a[1] = (short)f2bf(lrelu(bfhi(u.x)));
        a[2] = (short)f2bf(lrelu(bflo(u.y))); a[3] = (short)f2bf(lrelu(bfhi(u.y)));
        a[4] = (short)f2bf(lrelu(bflo(u.z))); a[5] = (short)f2bf(lrelu(bfhi(u.z)));
        a[6] = (short)f2bf(lrelu(bflo(u.w))); a[7] = (short)f2bf(lrelu(bfhi(u.w)));
        ha[ks] = a;
    }

    const bf8_t* gw1f = reinterpret_cast<const bf8_t*>(wf64 + 1536 * 8);
    f4_t acc[4];
    #pragma unroll
    for (int t = 0; t < 4; ++t) acc[t] = (f4_t){0.f, 0.f, 0.f, 0.f};
    #pragma unroll
    for (int ks = 0; ks < 2; ++ks)
        #pragma unroll
        for (int t = 0; t < 4; ++t)
            acc[t] = __builtin_amdgcn_mfma_f32_16x16x32_bf16(ha[ks], gw1f[(ks * 4 + t) * 64 + lane], acc[t], 0, 0, 0);

    int nn[4];
    #pragma unroll
    for (int reg = 0; reg < 4; ++reg) nn[reg] = rowBase + q * 4 + reg;

    #pragma unroll
    for (int t = 0; t < 4; ++t) {
        int colg = t * 16 + ql;
        float gbl = gb[colg];
        #pragma unroll
        for (int reg = 0; reg < 4; ++reg)
            if (nn[reg] < NUM_NODES) {
                size_t o = (size_t)nn[reg] * DIM_ID + colg;
                out[o] = lrelu(acc[t][reg] + gbl + bf2f(xhat[o]));
            }
    }
}

extern "C" void kernel_launch(void* const* d_in, const int* in_sizes, int n_in,
                              void* d_out, int out_size, void* d_ws, size_t ws_size,
                              hipStream_t stream)
{
    const float* features = (const float*)d_in[0];
    const float* idemb    = (const float*)d_in[1];
    const float* pref     = (const float*)d_in[2];
    const float* Wg0      = (const float*)d_in[3];
    const float* Wg1      = (const float*)d_in[4];
    const float* lw0      = (const float*)d_in[5];
    const float* lb0      = (const float*)d_in[6];
    const float* lw1      = (const float*)d_in[7];
    const float* lb1      = (const float*)d_in[8];
    const float* gw0      = (const float*)d_in[9];
    const float* gb0      = (const float*)d_in[10];
    const float* gw1      = (const float*)d_in[11];
    const float* gb1      = (const float*)d_in[12];
    const int*   edges    = (const int*)d_in[13];
    const int*   row      = edges;
    const int*   col      = edges + NUM_EDGES;

    char* ws = (char*)d_ws;
    int*      hist  = (int*)(ws + 0);             // 489*392*4 = 766,752 B (pad 1 MB)
    int*      bcnt  = (int*)(ws + 1048576);       // 4 KB
    int*      boff  = (int*)(ws + 1052672);       // 4 KB
    int*      offs  = (int*)(ws + 1056768);       // 512K
    int*      cnt   = (int*)(ws + 1581056);       // 512K
    float*    dis   = (float*)(ws + 2105344);     // 512K
    unsigned short* wfrag = (unsigned short*)(ws + 2629632);   // 64 KB
    unsigned short* wf64  = (unsigned short*)(ws + 2695168);   // 32 KB
    unsigned short* Hbf = (unsigned short*)(ws + 20000000);    // 12.8 MB
    unsigned* epk  = (unsigned*)(ws + 53960704);               // 8 MB (epack -> ecol in place)
    unsigned char*  hbf8  = (unsigned char*)(ws + 62349312);   // 6.4 MB + 64B sentinel row
    unsigned short* xhatb = (unsigned short*)(ws + 68749376);  // 12.8 MB -> 81.5 MB total
    float* out   = (float*)d_out;

    const int l1Blocks = NUM_NODES / 16;            // 6250 (K-split: 16 rows/block)
    const int midBlocks = (NUM_NODES + 63) / 64;    // 1563
    const int gatherBlocks = NUM_NODES / 4;         // 25000

    // ---- prep (wprep also zeroes the fp8 sentinel row) ----
    k_wprep<<<16, 256, 0, stream>>>(Wg0, lw0, wfrag, (unsigned*)hbf8);
    k_wprep64<<<8, 256, 0, stream>>>(gw0, Wg1, lw1, gw1, wf64);

    // ---- front: bucket histogram + scans, bin, CSR ----
    k_hist<<<NCHUNK, 256, 0, stream>>>(row, hist);
    k_off1<<<NBUCKET, 512, 0, stream>>>(hist, bcnt);
    k_bscan<<<1, 512, 0, stream>>>(bcnt, boff);
    k_bin2<<<NCHUNK, 256, 0, stream>>>(row, col, hist, boff, epk);
    k_csr<<<NBUCKET, 512, 0, stream>>>(epk, boff, offs, cnt, dis);

    // ---- layer 1 GEMM: K-split 4-wave, LDS-atomic reduction, fp8 table direct ----
    k_l1<<<l1Blocks, 256, 0, stream>>>(pref, features, wfrag, lb0, idemb, dis,
                                       hbf8, xhatb);

    // ---- layer 1 aggregate ----
    k_gather<<<gatherBlocks, 256, 0, stream>>>(hbf8, dis, offs, cnt, (const int*)epk, Hbf);

    // ---- combine1 + layer2 pre (fused, MFMA) ----
    k_mid<<<midBlocks, 256, 0, stream>>>(Hbf, xhatb, wf64, gb0, lb1, idemb, dis,
                                         hbf8, xhatb);

    // ---- layer 2 aggregate + final combine (MFMA) ----
    k_gather<<<gatherBlocks, 256, 0, stream>>>(hbf8, dis, offs, cnt, (const int*)epk, Hbf);
    k_final<<<midBlocks, 256, 0, stream>>>(Hbf, xhatb, wf64, gb1, out);
}

// Round 30
// 190.604 us; speedup vs baseline: 2.2504x; 2.2504x over previous
//
#include <hip/hip_runtime.h>

#define NUM_USER   50000
#define NUM_ITEM   50000
#define NUM_NODES  100000
#define DIM_LATENT 256
#define DIM_ID     64
#define NUM_EDGES  2000000
#define NBUCKET    391        // ceil(100000/256) buckets of 256 nodes
#define BPB        4096       // edges per chunk for counting sort
#define NCHUNK     489        // ceil(NUM_EDGES/BPB)
#define HSTRIDE    392
#define MAXBKT     8192       // max edges per bucket staged in LDS (avg 5115, ~37 sigma margin)
#define ZROW       NUM_NODES  // sentinel zero row in fp8 table

typedef __attribute__((ext_vector_type(8))) short bf8_t;
typedef __attribute__((ext_vector_type(4))) float f4_t;
typedef __attribute__((ext_vector_type(2))) float f2_t;

static __device__ __forceinline__ float lrelu(float x) {
    return x > 0.0f ? x : 0.01f * x;
}
static __device__ __forceinline__ unsigned short f2bf(float f) {
    unsigned u = __float_as_uint(f);
    u += 0x7fff + ((u >> 16) & 1);
    return (unsigned short)(u >> 16);
}
static __device__ __forceinline__ unsigned cvtpk_bf16(float lo, float hi) {
    unsigned r;
    asm("v_cvt_pk_bf16_f32 %0, %1, %2" : "=v"(r) : "v"(lo), "v"(hi));
    return r;
}
static __device__ __forceinline__ float bf2f(unsigned short u) {
    return __uint_as_float(((unsigned)u) << 16);
}
static __device__ __forceinline__ float bflo(unsigned u) {
    return __uint_as_float(u << 16);
}
static __device__ __forceinline__ float bfhi(unsigned u) {
    return __uint_as_float(u & 0xffff0000u);
}
static __device__ __forceinline__ f2_t shfl2(f2_t v, int off) {
    long long l = __shfl_xor(__builtin_bit_cast(long long, v), off);
    return __builtin_bit_cast(f2_t, l);
}

// ---------------- pass 1: per-chunk bucket histogram (LDS atomics only) ----------------
__global__ void __launch_bounds__(256) k_hist(const int* __restrict__ row,
                                              int* __restrict__ hist) {
    __shared__ int lh[NBUCKET];
    const int g = blockIdx.x, t = threadIdx.x;
    for (int i = t; i < NBUCKET; i += 256) lh[i] = 0;
    __syncthreads();
    const int base = g * BPB;
    for (int i = 0; i < BPB; i += 256) {
        int e = base + i + t;
        if (e < NUM_EDGES) atomicAdd(&lh[row[e] >> 8], 1);
    }
    __syncthreads();
    for (int i = t; i < NBUCKET; i += 256) hist[g * HSTRIDE + i] = lh[i];
}

// ---------------- pass 2a: per-bucket scan over 489 chunks (512 threads) ----------------
__global__ void __launch_bounds__(512) k_off1(int* __restrict__ hist,
                                              int* __restrict__ bcnt) {
    __shared__ int wsum[8];
    const int b = blockIdx.x, t = threadIdx.x;
    const int lane = t & 63, w = t >> 6;
    int c = (t < NCHUNK) ? hist[t * HSTRIDE + b] : 0;
    int v = c;
    #pragma unroll
    for (int off = 1; off < 64; off <<= 1) {
        int u = __shfl_up(v, off);
        if (lane >= off) v += u;
    }
    if (lane == 63) wsum[w] = v;
    __syncthreads();
    int add = 0;
    #pragma unroll
    for (int i = 0; i < 8; ++i) if (i < w) add += wsum[i];
    int incl = v + add;
    if (t < NCHUNK) hist[t * HSTRIDE + b] = incl - c;
    if (t == 511) bcnt[b] = incl;
}

// ---------------- pass 2b: exclusive scan over 391 bucket counts -> boff ----------------
__global__ void __launch_bounds__(512) k_bscan(const int* __restrict__ bcnt,
                                               int* __restrict__ boff) {
    __shared__ int wsum[8];
    const int t = threadIdx.x;
    const int lane = t & 63, w = t >> 6;
    int c = (t < NBUCKET) ? bcnt[t] : 0;
    int v = c;
    #pragma unroll
    for (int off = 1; off < 64; off <<= 1) {
        int u = __shfl_up(v, off);
        if (lane >= off) v += u;
    }
    if (lane == 63) wsum[w] = v;
    __syncthreads();
    int add = 0;
    #pragma unroll
    for (int i = 0; i < 8; ++i) if (i < w) add += wsum[i];
    int ex = v + add - c;
    if (t < NBUCKET) boff[t] = ex;
    if (t == NBUCKET - 1) boff[NBUCKET] = ex + c;   // == NUM_EDGES
}

// ---------------- pass 3: scatter packed edges to bucket-contiguous epk ----------------
// pack: (local_node << 24) | col   (col < 2^17)
__global__ void __launch_bounds__(256) k_bin2(const int* __restrict__ row,
                                              const int* __restrict__ col,
                                              const int* __restrict__ hist,
                                              const int* __restrict__ boff,
                                              unsigned* __restrict__ epk) {
    __shared__ int curs[NBUCKET];
    const int g = blockIdx.x, t = threadIdx.x;
    for (int i = t; i < NBUCKET; i += 256) curs[i] = boff[i] + hist[g * HSTRIDE + i];
    __syncthreads();
    const int base = g * BPB;
    for (int i = 0; i < BPB; i += 256) {
        int e = base + i + t;
        if (e < NUM_EDGES) {
            int r = row[e];
            int pos = atomicAdd(&curs[r >> 8], 1);
            epk[pos] = ((unsigned)(r & 255) << 24) | (unsigned)col[e];
        }
    }
}

// ---------------- pass 4: IN-PLACE bucket-local exact CSR via LDS staging ----------------
__global__ void __launch_bounds__(512) k_csr(unsigned* __restrict__ epk,
                                             const int* __restrict__ boff,
                                             int* __restrict__ offs,
                                             int* __restrict__ cnt,
                                             float* __restrict__ dis) {
    __shared__ unsigned stage[MAXBKT];   // 32 KB
    __shared__ int lcnt[256];
    __shared__ int lofs[256];
    __shared__ int wsum[4];
    const int b = blockIdx.x, t = threadIdx.x;
    const int start = boff[b];
    int m = boff[b + 1] - start;
    if (m > MAXBKT) m = MAXBKT;          // statistically unreachable guard

    if (t < 256) lcnt[t] = 0;
    for (int e = t; e < m; e += 512) stage[e] = epk[start + e];
    __syncthreads();
    for (int e = t; e < m; e += 512) atomicAdd(&lcnt[stage[e] >> 24], 1);
    __syncthreads();

    const int lane = t & 63, w = t >> 6;
    int c = (t < 256) ? lcnt[t] : 0;
    int v = c;
    #pragma unroll
    for (int off = 1; off < 64; off <<= 1) {
        int u = __shfl_up(v, off);
        if (lane >= off) v += u;
    }
    if (t < 256 && lane == 63) wsum[w] = v;
    __syncthreads();
    if (t < 256) {
        int add = 0;
        #pragma unroll
        for (int i = 0; i < 4; ++i) if (i < w) add += wsum[i];
        int ex = v + add - c;
        lofs[t] = start + ex;
        int n = (b << 8) + t;
        if (n < NUM_NODES) {
            offs[n] = start + ex;
            cnt[n]  = c;
            dis[n]  = rsqrtf((float)max(c, 1));
        }
    }
    __syncthreads();
    for (int e = t; e < m; e += 512) {
        unsigned p = stage[e];
        int pos = atomicAdd(&lofs[p >> 24], 1);
        epk[pos] = p & 0x00ffffffu;      // becomes ecol
    }
}

// ---------------- weight prep: Wg0,lw0 -> bf16 fragment table; block 0 zeroes sentinel ----------------
__global__ void __launch_bounds__(256) k_wprep(const float* __restrict__ Wg,
                                               const float* __restrict__ Wl,
                                               unsigned short* __restrict__ wfrag,
                                               unsigned* __restrict__ hbf8z) {
    if (blockIdx.x == 0 && threadIdx.x < 16)
        hbf8z[(size_t)ZROW * 16 + threadIdx.x] = 0u;   // 64B zero row
    int g = blockIdx.x * 256 + threadIdx.x;     // 4096 total
    if (g >= 4096) return;
    int ks = g >> 9;
    int t  = (g >> 6) & 7;
    int l  = g & 63;
    const float* W = (t < 4) ? Wg : Wl;
    int colg = (t & 3) * 16 + (l & 15);
    int kb = ks * 32 + (l >> 4) * 8;
    unsigned short o[8];
    #pragma unroll
    for (int e = 0; e < 8; ++e) o[e] = f2bf(W[(size_t)(kb + e) * DIM_ID + colg]);
    unsigned short* dst = wfrag + (size_t)g * 8;
    #pragma unroll
    for (int e = 0; e < 8; ++e) dst[e] = o[e];
}

// ---------------- weight prep: 4x 64x64 weights -> bf16 fragment tables ----------------
__global__ void __launch_bounds__(256) k_wprep64(const float* __restrict__ W0,
                                                 const float* __restrict__ W1,
                                                 const float* __restrict__ W2,
                                                 const float* __restrict__ W3,
                                                 unsigned short* __restrict__ frag) {
    int g = blockIdx.x * 256 + threadIdx.x;     // 2048 total
    if (g >= 2048) return;
    int m = g >> 9;
    int r = g & 511;
    int ks = r >> 8;
    int t  = (r >> 6) & 3;
    int l  = r & 63;
    const float* W = (m == 0) ? W0 : (m == 1) ? W1 : (m == 2) ? W2 : W3;
    int colg = t * 16 + (l & 15);
    int kb = ks * 32 + (l >> 4) * 8;
    unsigned short o[8];
    #pragma unroll
    for (int e = 0; e < 8; ++e) o[e] = f2bf(W[(size_t)(kb + e) * DIM_ID + colg]);
    unsigned short* dst = frag + (size_t)g * 8;
    #pragma unroll
    for (int e = 0; e < 8; ++e) dst[e] = o[e];
}

// ---------------- layer 1 (MFMA): K-SPLIT across 4 waves, TWO-PHASE partial exchange ----------------
// Block = 16 rows, 4 waves; wave w covers K in [64w, 64w+64) -> 4 float4 loads/wave.
// The 8 output tiles flow through ONE 16 KB accw buffer in two rounds (plain stores/reads,
// same f32 math and sum order as the 32 KB version): publish t0-3 -> waves 0,1 finalize stA;
// publish t4-7 -> waves 2,3 finalize stB. Total LDS ~21 KB -> 7 blocks/CU (vs 4 at 37 KB).
__global__ void __launch_bounds__(256, 7) k_l1(
    const float* __restrict__ pref, const float* __restrict__ feat,
    const unsigned short* __restrict__ wfrag,
    const float* __restrict__ lb,   const float* __restrict__ idemb,
    const float* __restrict__ dis,
    unsigned char* __restrict__ hbf8, unsigned short* __restrict__ xhat)
{
    __shared__ float accw[4][16][64];        // 16 KB, reused across the 2 phases
    __shared__ float ssb[4][16];             // per-wave row sq-sums
    __shared__ unsigned short stA[16][68];   // staged h (bf16, pre-fp8)
    __shared__ unsigned short stB[16][68];   // staged xhat (bf16, pre-idemb)
    const int t256 = threadIdx.x;
    const int lane = t256 & 63;
    const int w = t256 >> 6;                 // K-quarter 0..3
    const int ql = lane & 15, q = lane >> 4;
    const int rowBase = blockIdx.x * 16;
    const int rown = rowBase + ql;
    const float* src = (rown < NUM_USER) ? (pref + (size_t)rown * DIM_LATENT)
                                         : (feat + (size_t)(rown - NUM_USER) * DIM_LATENT);
    const int ks0 = 2 * w;

    // 4 loads per wave (compiler keeps these in flight)
    float4 v0 = *reinterpret_cast<const float4*>(src + ks0 * 32 + q * 8);
    float4 v1 = *reinterpret_cast<const float4*>(src + ks0 * 32 + q * 8 + 4);
    float4 v2 = *reinterpret_cast<const float4*>(src + (ks0 + 1) * 32 + q * 8);
    float4 v3 = *reinterpret_cast<const float4*>(src + (ks0 + 1) * 32 + q * 8 + 4);

    // partial squared-sum of row ql over this wave's K-range
    float ss = v0.x*v0.x + v0.y*v0.y + v0.z*v0.z + v0.w*v0.w
             + v1.x*v1.x + v1.y*v1.y + v1.z*v1.z + v1.w*v1.w
             + v2.x*v2.x + v2.y*v2.y + v2.z*v2.z + v2.w*v2.w
             + v3.x*v3.x + v3.y*v3.y + v3.z*v3.z + v3.w*v3.w;
    ss += __shfl_xor(ss, 16);
    ss += __shfl_xor(ss, 32);
    if (lane < 16) ssb[w][lane] = ss;

    // raw bf16 fragments for the 2 K-steps
    uint4 au0, au1;
    au0.x = cvtpk_bf16(v0.x, v0.y); au0.y = cvtpk_bf16(v0.z, v0.w);
    au0.z = cvtpk_bf16(v1.x, v1.y); au0.w = cvtpk_bf16(v1.z, v1.w);
    au1.x = cvtpk_bf16(v2.x, v2.y); au1.y = cvtpk_bf16(v2.z, v2.w);
    au1.z = cvtpk_bf16(v3.x, v3.y); au1.w = cvtpk_bf16(v3.z, v3.w);
    bf8_t a0 = __builtin_bit_cast(bf8_t, au0);
    bf8_t a1 = __builtin_bit_cast(bf8_t, au1);

    f4_t acc[8];
    #pragma unroll
    for (int t = 0; t < 8; ++t) acc[t] = (f4_t){0.f, 0.f, 0.f, 0.f};

    const bf8_t* wf = reinterpret_cast<const bf8_t*>(wfrag);
    #pragma unroll
    for (int t = 0; t < 8; ++t)
        acc[t] = __builtin_amdgcn_mfma_f32_16x16x32_bf16(a0, wf[(ks0 * 8 + t) * 64 + lane], acc[t], 0, 0, 0);
    #pragma unroll
    for (int t = 0; t < 8; ++t)
        acc[t] = __builtin_amdgcn_mfma_f32_16x16x32_bf16(a1, wf[((ks0 + 1) * 8 + t) * 64 + lane], acc[t], 0, 0, 0);

    // ---- phase 1: publish partials of tiles 0..3 ----
    #pragma unroll
    for (int t = 0; t < 4; ++t)
        #pragma unroll
        for (int reg = 0; reg < 4; ++reg)
            accw[w][t * 4 + reg][lane] = acc[t][reg];
    __syncthreads();   // partials + ssb visible

    // rn per C-layout row q*4+reg (sum ss over 4 waves)
    float rnl[4];
    #pragma unroll
    for (int reg = 0; reg < 4; ++reg) {
        int r = q * 4 + reg;
        float s = (ssb[0][r] + ssb[1][r]) + (ssb[2][r] + ssb[3][r]);
        rnl[reg] = 1.0f / fmaxf(sqrtf(s), 1e-12f);
    }

    // waves 0,1 finalize tiles 0..3 -> stA (h path)
    if (w < 2) {
        #pragma unroll
        for (int j = 0; j < 2; ++j) {
            int t = 2 * w + j;
            float av[4];
            #pragma unroll
            for (int reg = 0; reg < 4; ++reg)
                av[reg] = (accw[0][t * 4 + reg][lane] + accw[1][t * 4 + reg][lane])
                        + (accw[2][t * 4 + reg][lane] + accw[3][t * 4 + reg][lane]);
            int colg = t * 16 + ql;
            #pragma unroll
            for (int reg = 0; reg < 4; ++reg) {
                float dn = dis[rowBase + q * 4 + reg] * rnl[reg];
                stA[q * 4 + reg][colg] = f2bf(av[reg] * dn);
            }
        }
    }
    __syncthreads();   // phase-1 reads complete before buffer reuse

    // ---- phase 2: publish partials of tiles 4..7 into the same buffer ----
    #pragma unroll
    for (int t = 4; t < 8; ++t)
        #pragma unroll
        for (int reg = 0; reg < 4; ++reg)
            accw[w][(t - 4) * 4 + reg][lane] = acc[t][reg];
    __syncthreads();

    // waves 2,3 finalize tiles 4..7 -> stB (xhat path)
    if (w >= 2) {
        #pragma unroll
        for (int j = 0; j < 2; ++j) {
            int t = 2 * w + j;               // 4,5 (w=2) / 6,7 (w=3)
            int tp = t - 4;
            float av[4];
            #pragma unroll
            for (int reg = 0; reg < 4; ++reg)
                av[reg] = (accw[0][tp * 4 + reg][lane] + accw[1][tp * 4 + reg][lane])
                        + (accw[2][tp * 4 + reg][lane] + accw[3][tp * 4 + reg][lane]);
            int colg = tp * 16 + ql;
            float lbl = lb[colg];
            #pragma unroll
            for (int reg = 0; reg < 4; ++reg)
                stB[q * 4 + reg][colg] = f2bf(lrelu(av[reg] * rnl[reg] + lbl));
        }
    }
    __syncthreads();

    // writeout hbf8: 16 rows x 16 uints; one per thread
    {
        int r = t256 >> 4, c8 = t256 & 15;
        int n = rowBase + r;
        uint2 s = *reinterpret_cast<const uint2*>(&stA[r][c8 * 4]);
        int p = __builtin_amdgcn_cvt_pk_fp8_f32(bflo(s.x), bfhi(s.x), 0, false);
        p = __builtin_amdgcn_cvt_pk_fp8_f32(bflo(s.y), bfhi(s.y), p, true);
        *reinterpret_cast<unsigned*>(hbf8 + (size_t)n * DIM_ID + c8 * 4) = (unsigned)p;
    }
    // writeout xhat: 16 rows x 16 uint2 (+idemb); one per thread
    {
        int r = t256 >> 4, c8 = t256 & 15;
        int n = rowBase + r;
        uint2 s = *reinterpret_cast<const uint2*>(&stB[r][c8 * 4]);
        float4 idv = *reinterpret_cast<const float4*>(&idemb[(size_t)n * DIM_ID + c8 * 4]);
        uint2 o;
        o.x = cvtpk_bf16(bflo(s.x) + idv.x, bfhi(s.x) + idv.y);
        o.y = cvtpk_bf16(bflo(s.y) + idv.z, bfhi(s.y) + idv.w);
        *reinterpret_cast<uint2*>(&xhat[(size_t)n * DIM_ID + c8 * 4]) = o;
    }
}

// ---------------- gather: Hb[n] = bf16(dis[n] * sum_e hbf8[ecol[e]]) ----------------
// eighth-wave per edge; OOB slots read sentinel zero-row -> unpredicated inner loop
__global__ void __launch_bounds__(256, 8) k_gather(
    const unsigned char* __restrict__ hbf8, const float* __restrict__ dis,
    const int* __restrict__ offs, const int* __restrict__ cnt,
    const int* __restrict__ ecol, unsigned short* __restrict__ Hb)
{
    const int w = threadIdx.x >> 6;
    const int lane = threadIdx.x & 63;
    const int g = lane >> 3;      // edge slot 0..7
    const int k = lane & 7;       // dim octet 0..7
    const int n = blockIdx.x * 4 + w;

    const float dn = dis[n];
    const int start = offs[n];
    const int m = cnt[n];

    f2_t s01 = {0.f, 0.f}, s23 = {0.f, 0.f}, s45 = {0.f, 0.f}, s67 = {0.f, 0.f};

    for (int base = 0; base < m; base += 64) {
        int e = base + lane;
        int ec = (e < m) ? ecol[start + e] : ZROW;
        int lim = m - base; if (lim > 64) lim = 64;
        int ns = (lim + 31) >> 5;
        for (int s = 0; s < ns; ++s) {
            int i0 = s * 32 + g;
            int c0 = __shfl(ec, i0);
            int c1 = __shfl(ec, i0 + 8);
            int c2 = __shfl(ec, i0 + 16);
            int c3 = __shfl(ec, i0 + 24);
            uint2 u0 = *reinterpret_cast<const uint2*>(hbf8 + (size_t)(c0 << 6) + (k << 3));
            uint2 u1 = *reinterpret_cast<const uint2*>(hbf8 + (size_t)(c1 << 6) + (k << 3));
            uint2 u2 = *reinterpret_cast<const uint2*>(hbf8 + (size_t)(c2 << 6) + (k << 3));
            uint2 u3 = *reinterpret_cast<const uint2*>(hbf8 + (size_t)(c3 << 6) + (k << 3));
            s01 += __builtin_amdgcn_cvt_pk_f32_fp8(u0.x, false);
            s23 += __builtin_amdgcn_cvt_pk_f32_fp8(u0.x, true);
            s45 += __builtin_amdgcn_cvt_pk_f32_fp8(u0.y, false);
            s67 += __builtin_amdgcn_cvt_pk_f32_fp8(u0.y, true);
            s01 += __builtin_amdgcn_cvt_pk_f32_fp8(u1.x, false);
            s23 += __builtin_amdgcn_cvt_pk_f32_fp8(u1.x, true);
            s45 += __builtin_amdgcn_cvt_pk_f32_fp8(u1.y, false);
            s67 += __builtin_amdgcn_cvt_pk_f32_fp8(u1.y, true);
            s01 += __builtin_amdgcn_cvt_pk_f32_fp8(u2.x, false);
            s23 += __builtin_amdgcn_cvt_pk_f32_fp8(u2.x, true);
            s45 += __builtin_amdgcn_cvt_pk_f32_fp8(u2.y, false);
            s67 += __builtin_amdgcn_cvt_pk_f32_fp8(u2.y, true);
            s01 += __builtin_amdgcn_cvt_pk_f32_fp8(u3.x, false);
            s23 += __builtin_amdgcn_cvt_pk_f32_fp8(u3.x, true);
            s45 += __builtin_amdgcn_cvt_pk_f32_fp8(u3.y, false);
            s67 += __builtin_amdgcn_cvt_pk_f32_fp8(u3.y, true);
        }
    }
    #pragma unroll
    for (int off = 8; off <= 32; off <<= 1) {
        s01 += shfl2(s01, off);
        s23 += shfl2(s23, off);
        s45 += shfl2(s45, off);
        s67 += shfl2(s67, off);
    }
    if (lane < 8) {
        uint4 o;
        o.x = cvtpk_bf16(s01.x * dn, s01.y * dn);
        o.y = cvtpk_bf16(s23.x * dn, s23.y * dn);
        o.z = cvtpk_bf16(s45.x * dn, s45.y * dn);
        o.w = cvtpk_bf16(s67.x * dn, s67.y * dn);
        *reinterpret_cast<uint4*>(&Hb[(size_t)n * DIM_ID + lane * 8]) = o;
    }
}

// ---------------- mid (MFMA): x1 = lrelu(lrelu(H)@gw0+gb0+xhat1);
//                  hbf8 = fp8(dis*(x1@Wg1)); xhat2 = bf16(lrelu(x1@lw1+b1)+id) ----------------
__global__ void __launch_bounds__(256, 3) k_mid(
    const unsigned short* __restrict__ Hb, const unsigned short* __restrict__ xhat1,
    const unsigned short* __restrict__ wf64,
    const float* __restrict__ gb,  const float* __restrict__ lb1,
    const float* __restrict__ idemb, const float* __restrict__ dis,
    unsigned char* __restrict__ hbf8, unsigned short* __restrict__ xhat2)
{
    __shared__ unsigned short x1s[4][16][DIM_ID];
    __shared__ unsigned short st[4][16][68];
    const int lane = threadIdx.x & 63;
    const int w = threadIdx.x >> 6;
    const int ql = lane & 15, q = lane >> 4;
    const int rowBase = (blockIdx.x * 4 + w) * 16;
    const int rowc = min(rowBase + ql, NUM_NODES - 1);

    bf8_t ha[2];
    #pragma unroll
    for (int ks = 0; ks < 2; ++ks) {
        uint4 u = *reinterpret_cast<const uint4*>(&Hb[(size_t)rowc * DIM_ID + ks * 32 + q * 8]);
        bf8_t a;
        a[0] = (short)f2bf(lrelu(bflo(u.x))); a[1] = (short)f2bf(lrelu(bfhi(u.x)));
        a[2] = (short)f2bf(lrelu(bflo(u.y))); a[3] = (short)f2bf(lrelu(bfhi(u.y)));
        a[4] = (short)f2bf(lrelu(bflo(u.z))); a[5] = (short)f2bf(lrelu(bfhi(u.z)));
        a[6] = (short)f2bf(lrelu(bflo(u.w))); a[7] = (short)f2bf(lrelu(bfhi(u.w)));
        ha[ks] = a;
    }

    const bf8_t* gw0f = reinterpret_cast<const bf8_t*>(wf64);
    f4_t acc1[4];
    #pragma unroll
    for (int t = 0; t < 4; ++t) acc1[t] = (f4_t){0.f, 0.f, 0.f, 0.f};
    #pragma unroll
    for (int ks = 0; ks < 2; ++ks)
        #pragma unroll
        for (int t = 0; t < 4; ++t)
            acc1[t] = __builtin_amdgcn_mfma_f32_16x16x32_bf16(ha[ks], gw0f[(ks * 4 + t) * 64 + lane], acc1[t], 0, 0, 0);

    int nn[4];
    #pragma unroll
    for (int reg = 0; reg < 4; ++reg) nn[reg] = rowBase + q * 4 + reg;

    #pragma unroll
    for (int t = 0; t < 4; ++t) {
        int colg = t * 16 + ql;
        float gbl = gb[colg];
        #pragma unroll
        for (int reg = 0; reg < 4; ++reg) {
            float xh = bf2f(xhat1[(size_t)min(nn[reg], NUM_NODES - 1) * DIM_ID + colg]);
            x1s[w][q * 4 + reg][colg] = f2bf(lrelu(acc1[t][reg] + gbl + xh));
        }
    }
    __syncthreads();

    bf8_t xa[2];
    #pragma unroll
    for (int ks = 0; ks < 2; ++ks)
        xa[ks] = *reinterpret_cast<const bf8_t*>(&x1s[w][ql][ks * 32 + q * 8]);

    const bf8_t* wg1f = reinterpret_cast<const bf8_t*>(wf64 + 512 * 8);
    const bf8_t* lw1f = reinterpret_cast<const bf8_t*>(wf64 + 1024 * 8);
    f4_t acc2[8];
    #pragma unroll
    for (int t = 0; t < 8; ++t) acc2[t] = (f4_t){0.f, 0.f, 0.f, 0.f};
    #pragma unroll
    for (int ks = 0; ks < 2; ++ks) {
        #pragma unroll
        for (int t = 0; t < 4; ++t)
            acc2[t] = __builtin_amdgcn_mfma_f32_16x16x32_bf16(xa[ks], wg1f[(ks * 4 + t) * 64 + lane], acc2[t], 0, 0, 0);
        #pragma unroll
        for (int t = 0; t < 4; ++t)
            acc2[4 + t] = __builtin_amdgcn_mfma_f32_16x16x32_bf16(xa[ks], lw1f[(ks * 4 + t) * 64 + lane], acc2[4 + t], 0, 0, 0);
    }

    float dn[4];
    #pragma unroll
    for (int reg = 0; reg < 4; ++reg)
        dn[reg] = (nn[reg] < NUM_NODES) ? dis[nn[reg]] : 0.0f;

    // ---- phase A: hbf8 = fp8(acc2[0..3]*dn) via LDS -> coalesced uint ----
    #pragma unroll
    for (int t = 0; t < 4; ++t)
        #pragma unroll
        for (int reg = 0; reg < 4; ++reg)
            st[w][q * 4 + reg][t * 16 + ql] = f2bf(acc2[t][reg] * dn[reg]);
    #pragma unroll
    for (int it = 0; it < 4; ++it) {
        int i = it * 64 + lane;
        int r = i >> 4, c8 = i & 15;
        int n = rowBase + r;
        uint2 s = *reinterpret_cast<const uint2*>(&st[w][r][c8 * 4]);
        if (n < NUM_NODES) {
            int p = __builtin_amdgcn_cvt_pk_fp8_f32(bflo(s.x), bfhi(s.x), 0, false);
            p = __builtin_amdgcn_cvt_pk_fp8_f32(bflo(s.y), bfhi(s.y), p, true);
            *reinterpret_cast<unsigned*>(hbf8 + (size_t)n * DIM_ID + c8 * 4) = (unsigned)p;
        }
    }

    // ---- phase B: xhat2 = lrelu(acc2[4..7]+lb1) (+idemb coalesced) ----
    #pragma unroll
    for (int t = 0; t < 4; ++t) {
        int colg = t * 16 + ql;
        float lbl = lb1[colg];
        #pragma unroll
        for (int reg = 0; reg < 4; ++reg)
            st[w][q * 4 + reg][colg] = f2bf(lrelu(acc2[4 + t][reg] + lbl));
    }
    #pragma unroll
    for (int it = 0; it < 4; ++it) {
        int i = it * 64 + lane;
        int r = i >> 4, c8 = i & 15;
        int n = rowBase + r;
        if (n < NUM_NODES) {
            uint2 s = *reinterpret_cast<const uint2*>(&st[w][r][c8 * 4]);
            float4 idv = *reinterpret_cast<const float4*>(&idemb[(size_t)n * DIM_ID + c8 * 4]);
            uint2 o;
            o.x = cvtpk_bf16(bflo(s.x) + idv.x, bfhi(s.x) + idv.y);
            o.y = cvtpk_bf16(bflo(s.y) + idv.z, bfhi(s.y) + idv.w);
            *reinterpret_cast<uint2*>(&xhat2[(size_t)n * DIM_ID + c8 * 4]) = o;
        }
    }
}

// ---------------- final (MFMA): out = lrelu(lrelu(H2)@gw1 + gb1 + xhat2) ----------------
__global__ void __launch_bounds__(256, 3) k_final(
    const unsigned short* __restrict__ Hb, const unsigned short* __restrict__ xhat,
    const unsigned short* __restrict__ wf64,
    const float* __restrict__ gb, float* __restrict__ out)
{
    const int lane = threadIdx.x & 63;
    const int w = threadIdx.x >> 6;
    const int ql = lane & 15, q = lane >> 4;
    const int rowBase = (blockIdx.x * 4 + w) * 16;
    const int rowc = min(rowBase + ql, NUM_NODES - 1);

    bf8_t ha[2];
    #pragma unroll
    for (int ks = 0; ks < 2; ++ks) {
        uint4 u = *reinterpret_cast<const uint4*>(&Hb[(size_t)rowc * DIM_ID + ks * 32 + q * 8]);
        bf8_t a;
        a[0] = (short)f2bf(lrelu(bflo(u.x))); a[1] = (short)f2bf(lrelu(bfhi(u.x)));
        a[2] = (short)f2bf(lrelu(bflo(u.y))); a[3] = (short)f2bf(lrelu(bfhi(u.y)));
        a[4] = (short)f2bf(lrelu(bflo(u.z))); a[5] = (short)f2bf(lrelu(bfhi(u.z)));
        a[6] = (short)f2bf(lrelu(bflo(u.w))); a[7] = (short)f2bf(lrelu(bfhi(u.w)));
        ha[ks] = a;
    }

    const bf8_t* gw1f = reinterpret_cast<const bf8_t*>(wf64 + 1536 * 8);
    f4_t acc[4];
    #pragma unroll
    for (int t = 0; t < 4; ++t) acc[t] = (f4_t){0.f, 0.f, 0.f, 0.f};
    #pragma unroll
    for (int ks = 0; ks < 2; ++ks)
        #pragma unroll
        for (int t = 0; t < 4; ++t)
            acc[t] = __builtin_amdgcn_mfma_f32_16x16x32_bf16(ha[ks], gw1f[(ks * 4 + t) * 64 + lane], acc[t], 0, 0, 0);

    int nn[4];
    #pragma unroll
    for (int reg = 0; reg < 4; ++reg) nn[reg] = rowBase + q * 4 + reg;

    #pragma unroll
    for (int t = 0; t < 4; ++t) {
        int colg = t * 16 + ql;
        float gbl = gb[colg];
        #pragma unroll
        for (int reg = 0; reg < 4; ++reg)
            if (nn[reg] < NUM_NODES) {
                size_t o = (size_t)nn[reg] * DIM_ID + colg;
                out[o] = lrelu(acc[t][reg] + gbl + bf2f(xhat[o]));
            }
    }
}

extern "C" void kernel_launch(void* const* d_in, const int* in_sizes, int n_in,
                              void* d_out, int out_size, void* d_ws, size_t ws_size,
                              hipStream_t stream)
{
    const float* features = (const float*)d_in[0];
    const float* idemb    = (const float*)d_in[1];
    const float* pref     = (const float*)d_in[2];
    const float* Wg0      = (const float*)d_in[3];
    const float* Wg1      = (const float*)d_in[4];
    const float* lw0      = (const float*)d_in[5];
    const float* lb0      = (const float*)d_in[6];
    const float* lw1      = (const float*)d_in[7];
    const float* lb1      = (const float*)d_in[8];
    const float* gw0      = (const float*)d_in[9];
    const float* gb0      = (const float*)d_in[10];
    const float* gw1      = (const float*)d_in[11];
    const float* gb1      = (const float*)d_in[12];
    const int*   edges    = (const int*)d_in[13];
    const int*   row      = edges;
    const int*   col      = edges + NUM_EDGES;

    char* ws = (char*)d_ws;
    int*      hist  = (int*)(ws + 0);             // 489*392*4 = 766,752 B (pad 1 MB)
    int*      bcnt  = (int*)(ws + 1048576);       // 4 KB
    int*      boff  = (int*)(ws + 1052672);       // 4 KB
    int*      offs  = (int*)(ws + 1056768);       // 512K
    int*      cnt   = (int*)(ws + 1581056);       // 512K
    float*    dis   = (float*)(ws + 2105344);     // 512K
    unsigned short* wfrag = (unsigned short*)(ws + 2629632);   // 64 KB
    unsigned short* wf64  = (unsigned short*)(ws + 2695168);   // 32 KB
    unsigned short* Hbf = (unsigned short*)(ws + 20000000);    // 12.8 MB
    unsigned* epk  = (unsigned*)(ws + 53960704);               // 8 MB (epack -> ecol in place)
    unsigned char*  hbf8  = (unsigned char*)(ws + 62349312);   // 6.4 MB + 64B sentinel row
    unsigned short* xhatb = (unsigned short*)(ws + 68749376);  // 12.8 MB -> 81.5 MB total
    float* out   = (float*)d_out;

    const int l1Blocks = NUM_NODES / 16;            // 6250 (K-split: 16 rows/block)
    const int midBlocks = (NUM_NODES + 63) / 64;    // 1563
    const int gatherBlocks = NUM_NODES / 4;         // 25000

    // ---- prep (wprep also zeroes the fp8 sentinel row) ----
    k_wprep<<<16, 256, 0, stream>>>(Wg0, lw0, wfrag, (unsigned*)hbf8);
    k_wprep64<<<8, 256, 0, stream>>>(gw0, Wg1, lw1, gw1, wf64);

    // ---- front: bucket histogram + scans, bin, CSR ----
    k_hist<<<NCHUNK, 256, 0, stream>>>(row, hist);
    k_off1<<<NBUCKET, 512, 0, stream>>>(hist, bcnt);
    k_bscan<<<1, 512, 0, stream>>>(bcnt, boff);
    k_bin2<<<NCHUNK, 256, 0, stream>>>(row, col, hist, boff, epk);
    k_csr<<<NBUCKET, 512, 0, stream>>>(epk, boff, offs, cnt, dis);

    // ---- layer 1 GEMM: K-split 4-wave, two-phase partial exchange ----
    k_l1<<<l1Blocks, 256, 0, stream>>>(pref, features, wfrag, lb0, idemb, dis,
                                       hbf8, xhatb);

    // ---- layer 1 aggregate ----
    k_gather<<<gatherBlocks, 256, 0, stream>>>(hbf8, dis, offs, cnt, (const int*)epk, Hbf);

    // ---- combine1 + layer2 pre (fused, MFMA) ----
    k_mid<<<midBlocks, 256, 0, stream>>>(Hbf, xhatb, wf64, gb0, lb1, idemb, dis,
                                         hbf8, xhatb);

    // ---- layer 2 aggregate + final combine (MFMA) ----
    k_gather<<<gatherBlocks, 256, 0, stream>>>(hbf8, dis, offs, cnt, (const int*)epk, Hbf);
    k_final<<<midBlocks, 256, 0, stream>>>(Hbf, xhatb, wf64, gb1, out);
}